// Round 5
// baseline (1334.512 us; speedup 1.0000x reference)
//
#include <hip/hip_runtime.h>
#include <cstdint>
#include <cstddef>

#define N_USERS 100000
#define N_ITEMS 50000
#define DIM     64
#define IMG_D   1024
#define TXT_D   384
#define N_EDGES 2000000
#define N_COMB  (N_USERS + N_ITEMS)

// privatized histogram: 64 block-private count arrays (workgroup-scope atomics)
#define NPRIV  64
#define ECHUNK ((N_EDGES + NPRIV - 1) / NPRIV)  // 31250

// d_out layout (floats), concatenated in reference return order
#define OFF_UOUT 0
#define OFF_IOUT (N_USERS * DIM)
#define OFF_IIT  (OFF_IOUT + N_ITEMS * DIM)
#define OFF_TIT  (OFF_IIT + N_ITEMS * DIM)
#define OFF_IUS  (OFF_TIT + N_ITEMS * DIM)
#define OFF_TUS  (OFF_IUS + N_USERS * DIM)

typedef __attribute__((ext_vector_type(8))) short short8;
typedef __attribute__((ext_vector_type(4))) float float4v;
typedef __attribute__((ext_vector_type(4))) unsigned int uint4v;
typedef __attribute__((ext_vector_type(4))) _Float16 half4v;

__device__ __forceinline__ float wave_sum64(float v) {
#pragma unroll
  for (int off = 32; off; off >>= 1) v += __shfl_xor(v, off, 64);
  return v;
}

__device__ __forceinline__ unsigned int pack_bf16(float x, float y) {
  const unsigned int xu = __float_as_uint(x) + 0x8000u;
  const unsigned int yu = __float_as_uint(y) + 0x8000u;
  return (xu >> 16) | (yu & 0xffff0000u);
}

// a += w * (float)x[0..3]
__device__ __forceinline__ float4v fma4h(float w, const half4v x, float4v a) {
#pragma unroll
  for (int j = 0; j < 4; ++j) a[j] = fmaf(w, (float)x[j], a[j]);
  return a;
}

__device__ __forceinline__ half4v to_h4(const float4v a) {
  half4v h;
#pragma unroll
  for (int j = 0; j < 4; ++j) h[j] = (_Float16)a[j];
  return h;
}

// packed CSR record: {col[16:0] << 15 | fp16_bits(w)[14:0]}  (w >= 0 so sign bit = 0)
__device__ __forceinline__ void dec_rec(unsigned int rec, int& c, float& w) {
  c = (int)(rec >> 15);
  w = (float)__builtin_bit_cast(_Float16, (unsigned short)(rec & 0x7FFFu));
}

__device__ __forceinline__ unsigned int enc_rec(int c, float w) {
  const unsigned short hb = __builtin_bit_cast(unsigned short, (_Float16)w);
  return ((unsigned int)c << 15) | (unsigned int)hb;
}

// ---------------- CSR build (privatized, no device-scope atomics) ----------------
// Each block owns a private count slice; workgroup-scope atomicAdd executes in the
// XCD-local L2 instead of the memory-side coherence point (device-scope rate was
// measured at ~22 Gops/s = 185 us for 4M ops). Return value = rank within chunk.
__global__ __launch_bounds__(256) void hist_priv_kernel(
    const int* __restrict__ eu, const int* __restrict__ ei,
    int* __restrict__ priv_u, int* __restrict__ priv_i,
    int* __restrict__ pe_u, int* __restrict__ pe_i) {
  const int b = blockIdx.x;
  int* __restrict__ pu = priv_u + (size_t)b * N_USERS;
  int* __restrict__ pi = priv_i + (size_t)b * N_ITEMS;
  const int s = b * ECHUNK;
  const int e = min(s + ECHUNK, N_EDGES);
  for (int i = s + (int)threadIdx.x; i < e; i += 256) {
    const int u = eu[i], it = ei[i];
    pe_u[i] = __hip_atomic_fetch_add(&pu[u], 1, __ATOMIC_RELAXED,
                                     __HIP_MEMORY_SCOPE_WORKGROUP);
    pe_i[i] = __hip_atomic_fetch_add(&pi[it], 1, __ATOMIC_RELAXED,
                                     __HIP_MEMORY_SCOPE_WORKGROUP);
  }
}

// totals: cnt[key] = sum_b priv[b][key]
__global__ __launch_bounds__(256) void sum_priv_kernel(
    const int* __restrict__ priv_u, const int* __restrict__ priv_i,
    int* __restrict__ cnt_u, int* __restrict__ cnt_i) {
  const int t = blockIdx.x * 256 + threadIdx.x;
  if (t < N_USERS) {
    int ssum = 0;
#pragma unroll 4
    for (int b = 0; b < NPRIV; ++b) ssum += priv_u[(size_t)b * N_USERS + t];
    cnt_u[t] = ssum;
  } else if (t < N_USERS + N_ITEMS) {
    const int k = t - N_USERS;
    int ssum = 0;
#pragma unroll 4
    for (int b = 0; b < NPRIV; ++b) ssum += priv_i[(size_t)b * N_ITEMS + k];
    cnt_i[k] = ssum;
  }
}

// block 0: users, block 1: items — runs both scans concurrently
__global__ __launch_bounds__(1024) void scan2_kernel(const int* __restrict__ cnt_u,
                                                     int* __restrict__ rs_u,
                                                     const int* __restrict__ cnt_i,
                                                     int* __restrict__ rs_i) {
  const int* counts;
  int *rs, n;
  if (blockIdx.x == 0) { counts = cnt_u; rs = rs_u; n = N_USERS; }
  else                 { counts = cnt_i; rs = rs_i; n = N_ITEMS; }
  __shared__ int part[1024];
  const int t = threadIdx.x;
  const int chunk = (n + 1023) >> 10;
  const int b = t * chunk;
  const int e = min(b + chunk, n);
  int s = 0;
  for (int j = b; j < e; ++j) s += counts[j];
  part[t] = s;
  __syncthreads();
  for (int off = 1; off < 1024; off <<= 1) {
    const int add = (t >= off) ? part[t - off] : 0;
    __syncthreads();
    part[t] += add;
    __syncthreads();
  }
  int run = (t == 0) ? 0 : part[t - 1];
  for (int j = b; j < e; ++j) {
    rs[j] = run;
    run += counts[j];
  }
  if (t == 1023) rs[n] = part[1023];
}

// base: priv[b][key] = rs[key] + prefix over earlier blocks
__global__ __launch_bounds__(256) void base_priv_kernel(
    int* __restrict__ priv_u, int* __restrict__ priv_i,
    const int* __restrict__ rs_u, const int* __restrict__ rs_i) {
  const int t = blockIdx.x * 256 + threadIdx.x;
  if (t < N_USERS) {
    int run = rs_u[t];
    for (int b = 0; b < NPRIV; ++b) {
      const size_t idx = (size_t)b * N_USERS + t;
      const int c = priv_u[idx];
      priv_u[idx] = run;
      run += c;
    }
  } else if (t < N_USERS + N_ITEMS) {
    const int k = t - N_USERS;
    int run = rs_i[k];
    for (int b = 0; b < NPRIV; ++b) {
      const size_t idx = (size_t)b * N_ITEMS + k;
      const int c = priv_i[idx];
      priv_i[idx] = run;
      run += c;
    }
  }
}

// atomic-free fill: pos = priv_base[chunk][row] + rank; one 4B scattered store/edge/side
__global__ __launch_bounds__(256) void fill_kernel(
    const int* __restrict__ eu, const int* __restrict__ ei,
    const float* __restrict__ vui, const float* __restrict__ viu,
    const int* __restrict__ pe_u, const int* __restrict__ pe_i,
    const int* __restrict__ priv_u, const int* __restrict__ priv_i,
    unsigned int* __restrict__ cw_u, unsigned int* __restrict__ cw_i) {
  const int i = blockIdx.x * 256 + threadIdx.x;
  if (i < N_EDGES) {
    const int b = i / ECHUNK;  // constant within a block except at chunk edges
    const int u = eu[i], it = ei[i];
    const int p = priv_u[(size_t)b * N_USERS + u] + pe_u[i];
    const int q = priv_i[(size_t)b * N_ITEMS + it] + pe_i[i];
    cw_u[p] = enc_rec(it, vui[i]);
    cw_i[q] = enc_rec(u, viu[i]);
  }
}

// ---------------- W pre-swizzle into MFMA B-fragment layout (bf16) ----------------
__global__ __launch_bounds__(256) void wswizzle_kernel(const float* __restrict__ Wimg,
                                                       const float* __restrict__ Wtxt,
                                                       unsigned short* __restrict__ WBimg,
                                                       unsigned short* __restrict__ WBtxt) {
  int t = blockIdx.x * 256 + threadIdx.x;
  const float* W;
  unsigned short* WB;
  if (t < 8192) { W = Wimg; WB = WBimg; }
  else if (t < 8192 + 3072) { t -= 8192; W = Wtxt; WB = WBtxt; }
  else return;
  const int frag = t >> 6;
  const int lane = t & 63;
  const int K0idx = frag >> 2;
  const int n0idx = frag & 3;
  const int k0 = K0idx * 32 + ((lane >> 4) << 3);
  const int c = n0idx * 16 + (lane & 15);
  unsigned short us[8];
#pragma unroll
  for (int j = 0; j < 8; ++j) {
    const unsigned int b = __float_as_uint(W[(size_t)(k0 + j) * 64 + c]) + 0x8000u;
    us[j] = (unsigned short)(b >> 16);
  }
  uint4v o;
  o.x = (unsigned int)us[0] | ((unsigned int)us[1] << 16);
  o.y = (unsigned int)us[2] | ((unsigned int)us[3] << 16);
  o.z = (unsigned int)us[4] | ((unsigned int)us[5] << 16);
  o.w = (unsigned int)us[6] | ((unsigned int)us[7] << 16);
  *reinterpret_cast<uint4v*>(WB + (size_t)t * 8) = o;
}

// ---------------- MFMA GEMM: wave = 16 rows x 64 cols, no LDS ----------------
// output goes straight to the fp16 packed gather table g_items[item][192]:
// cols [0:64]=img feat, [64:128]=txt feat ([128:192]=i0, written by normalize)
__global__ __launch_bounds__(256) void mfma_gemm_kernel(
    const float* __restrict__ Ximg, const unsigned short* __restrict__ WBimg,
    const float* __restrict__ bimg,
    const float* __restrict__ Xtxt, const unsigned short* __restrict__ WBtxt,
    const float* __restrict__ btxt,
    _Float16* __restrict__ g_items) {
  const int TILES_IMG = N_ITEMS / 16;  // 3125
  const int wv = threadIdx.x >> 6;
  const int lane = threadIdx.x & 63;
  int tile = blockIdx.x * 4 + wv;
  if (tile >= 2 * TILES_IMG) return;

  const float* X;
  const unsigned short* WB;
  const float* bias;
  int K, nK0, c0;
  if (tile < TILES_IMG) { X = Ximg; WB = WBimg; bias = bimg; K = IMG_D; nK0 = IMG_D / 32; c0 = 0; }
  else { tile -= TILES_IMG; X = Xtxt; WB = WBtxt; bias = btxt; K = TXT_D; nK0 = TXT_D / 32; c0 = 64; }

  const int row0 = tile * 16;
  const int m = lane & 15;
  const int koff = (lane >> 4) << 3;
  const float* __restrict__ xp = X + (size_t)(row0 + m) * K + koff;
  const short8* __restrict__ wb8 = reinterpret_cast<const short8*>(WB);

  float4v acc[4];
#pragma unroll
  for (int n0 = 0; n0 < 4; ++n0) acc[n0] = (float4v){0.f, 0.f, 0.f, 0.f};

  for (int K0 = 0; K0 < nK0; ++K0) {
    const float4 xa = *reinterpret_cast<const float4*>(xp + K0 * 32);
    const float4 xb = *reinterpret_cast<const float4*>(xp + K0 * 32 + 4);
    uint4v au;
    au.x = pack_bf16(xa.x, xa.y);
    au.y = pack_bf16(xa.z, xa.w);
    au.z = pack_bf16(xb.x, xb.y);
    au.w = pack_bf16(xb.z, xb.w);
    const short8 af = __builtin_bit_cast(short8, au);
#pragma unroll
    for (int n0 = 0; n0 < 4; ++n0) {
      const short8 bf = wb8[(size_t)(K0 * 4 + n0) * 64 + lane];
      acc[n0] = __builtin_amdgcn_mfma_f32_16x16x32_bf16(af, bf, acc[n0], 0, 0, 0);
    }
  }

  // C/D: col = lane&15, row = (lane>>4)*4 + reg
  const int crow = (lane >> 4) << 2;
  const int ccol = lane & 15;
#pragma unroll
  for (int n0 = 0; n0 < 4; ++n0) {
    const float bv = bias[n0 * 16 + ccol];
#pragma unroll
    for (int r = 0; r < 4; ++r) {
      g_items[(size_t)(row0 + crow + r) * 192 + c0 + n0 * 16 + ccol] =
          (_Float16)(acc[n0][r] + bv);
    }
  }
}

// ---------------- normalization statistics ----------------
__global__ __launch_bounds__(256) void stats_kernel(const float* __restrict__ ue,
                                                    const float* __restrict__ ie,
                                                    float* __restrict__ stats) {
  const int t = threadIdx.x;
  const int lane = t & 63;
  float cs = 0.f, ss = 0.f;
  const size_t total = (size_t)N_COMB * DIM;
  const size_t ubound = (size_t)N_USERS * DIM;
  const size_t stride = (size_t)gridDim.x * blockDim.x;
  for (size_t i = (size_t)blockIdx.x * blockDim.x + t; i < total; i += stride) {
    const float v = (i < ubound) ? ue[i] : ie[i - ubound];
    cs += v;
    ss += v * v;
  }
  ss = wave_sum64(ss);
  __shared__ float lcol[4][64];
  __shared__ float lss[4];
  const int wv = t >> 6;
  lcol[wv][lane] = cs;
  if (lane == 0) lss[wv] = ss;
  __syncthreads();
  if (wv == 0) {
    const float c = lcol[0][lane] + lcol[1][lane] + lcol[2][lane] + lcol[3][lane];
    atomicAdd(&stats[lane], c);
    if (lane == 0) atomicAdd(&stats[64], lss[0] + lss[1] + lss[2] + lss[3]);
  }
}

__global__ void finalize_kernel(float* __restrict__ stats) {
  const int d = threadIdx.x;  // 64 threads
  const float ssum = stats[64];
  const float m = stats[d] / (float)N_COMB;
  const float m2sum = wave_sum64(m * m);
  const float tot = ssum - (float)N_COMB * m2sum;
  const float rnm = sqrtf(tot / (float)N_COMB + 1e-6f);
  stats[d] = m;
  if (d == 0) stats[64] = 1.f / rnm;
}

// writes u_acc/i_acc fp32 (GNN accumulators in d_out) + i0 in fp16 to g_items[:,128:192]
__global__ __launch_bounds__(256) void normalize_kernel(
    const float* __restrict__ ue, const float* __restrict__ ie, const float* __restrict__ stats,
    float* __restrict__ uacc, float* __restrict__ iacc, _Float16* __restrict__ g_items) {
  const int lane = threadIdx.x & 63;
  const float m = stats[lane];
  const float inv = stats[64];
  const size_t total = (size_t)N_COMB * DIM;
  const size_t ubound = (size_t)N_USERS * DIM;
  const size_t stride = (size_t)gridDim.x * blockDim.x;
  for (size_t i = (size_t)blockIdx.x * blockDim.x + threadIdx.x; i < total; i += stride) {
    if (i < ubound) {
      uacc[i] = (ue[i] - m) * inv;
    } else {
      const size_t j = i - ubound;
      const float v = (ie[j] - m) * inv;
      iacc[j] = v;
      g_items[(j >> 6) * 192 + 128 + (j & 63)] = (_Float16)v;
    }
  }
}

// ---------------- triple SPMM over packed fp16 rows ----------------
// {a1,a2,a3}[r] = sum_k w[k] * G[col[k]][{0,64,128}+:64]
// writes O1,O2 fp32; acc += a3; and fp16: either all three into gout192[r][192]
// or just a3 into gout64[r][64].
__global__ __launch_bounds__(256) void spmm_triple_kernel(
    const int* __restrict__ rs, const unsigned int* __restrict__ cw,
    const _Float16* __restrict__ G,
    float* __restrict__ O1, float* __restrict__ O2,
    float* __restrict__ acc,
    _Float16* __restrict__ gout192, _Float16* __restrict__ gout64, int nrows) {
  const int lane = threadIdx.x & 63;
  const int wv = __builtin_amdgcn_readfirstlane(threadIdx.x >> 6);
  const int r = blockIdx.x * 4 + wv;
  if (r >= nrows) return;
  const int q = lane >> 4;
  const int l = lane & 15;
  const int s = rs[r], e = rs[r + 1];
  float4v a1 = {0.f, 0.f, 0.f, 0.f};
  float4v a2 = {0.f, 0.f, 0.f, 0.f};
  float4v a3 = {0.f, 0.f, 0.f, 0.f};
  int k = s + q;
  for (; k + 4 < e; k += 8) {
    int c0, c1;
    float w0, w1;
    dec_rec(cw[k], c0, w0);
    dec_rec(cw[k + 4], c1, w1);
    const _Float16* g0 = G + (size_t)c0 * 192 + l * 4;
    const _Float16* g1 = G + (size_t)c1 * 192 + l * 4;
    const half4v x10 = *reinterpret_cast<const half4v*>(g0);
    const half4v x20 = *reinterpret_cast<const half4v*>(g0 + 64);
    const half4v x30 = *reinterpret_cast<const half4v*>(g0 + 128);
    const half4v x11 = *reinterpret_cast<const half4v*>(g1);
    const half4v x21 = *reinterpret_cast<const half4v*>(g1 + 64);
    const half4v x31 = *reinterpret_cast<const half4v*>(g1 + 128);
    a1 = fma4h(w0, x10, a1);
    a2 = fma4h(w0, x20, a2);
    a3 = fma4h(w0, x30, a3);
    a1 = fma4h(w1, x11, a1);
    a2 = fma4h(w1, x21, a2);
    a3 = fma4h(w1, x31, a3);
  }
  if (k < e) {
    int c0;
    float w0;
    dec_rec(cw[k], c0, w0);
    const _Float16* g0 = G + (size_t)c0 * 192 + l * 4;
    a1 = fma4h(w0, *reinterpret_cast<const half4v*>(g0), a1);
    a2 = fma4h(w0, *reinterpret_cast<const half4v*>(g0 + 64), a2);
    a3 = fma4h(w0, *reinterpret_cast<const half4v*>(g0 + 128), a3);
  }
  // combine quarter partials: xor 16 then 32 sums over the 4 quarters
#pragma unroll
  for (int j = 0; j < 4; ++j) {
    a1[j] += __shfl_xor(a1[j], 16, 64);
    a1[j] += __shfl_xor(a1[j], 32, 64);
    a2[j] += __shfl_xor(a2[j], 16, 64);
    a2[j] += __shfl_xor(a2[j], 32, 64);
    a3[j] += __shfl_xor(a3[j], 16, 64);
    a3[j] += __shfl_xor(a3[j], 32, 64);
  }
  if (q == 0) {
    const size_t o = (size_t)r * 64 + l * 4;
    *reinterpret_cast<float4v*>(O1 + o) = a1;
    *reinterpret_cast<float4v*>(O2 + o) = a2;
    float4v av = *reinterpret_cast<const float4v*>(acc + o);
#pragma unroll
    for (int j = 0; j < 4; ++j) av[j] += a3[j];
    *reinterpret_cast<float4v*>(acc + o) = av;
    if (gout192) {
      _Float16* gr = gout192 + (size_t)r * 192 + l * 4;
      *reinterpret_cast<half4v*>(gr) = to_h4(a1);
      *reinterpret_cast<half4v*>(gr + 64) = to_h4(a2);
      *reinterpret_cast<half4v*>(gr + 128) = to_h4(a3);
    } else {
      *reinterpret_cast<half4v*>(gout64 + o) = to_h4(a3);
    }
  }
}

// ---------------- final SPMM + fused epilogue ----------------
// a = (A @ X)[r]; if(GO) GO[r]=fp16(a); accio[r] = (accio[r]+a)/3 + .55*l2n(P[r]) + .55*l2n(Q[r])
__global__ __launch_bounds__(256) void spmm_final_kernel(
    const int* __restrict__ rs, const unsigned int* __restrict__ cw,
    const _Float16* __restrict__ X, _Float16* __restrict__ GO,
    const float* __restrict__ P, const float* __restrict__ Q,
    float* __restrict__ accio, int nrows) {
  const int lane = threadIdx.x & 63;
  const int wv = __builtin_amdgcn_readfirstlane(threadIdx.x >> 6);
  const int r = blockIdx.x * 4 + wv;
  if (r >= nrows) return;
  const int q = lane >> 4;
  const int l = lane & 15;
  const int s = rs[r], e = rs[r + 1];
  float4v a = {0.f, 0.f, 0.f, 0.f};
  int k = s + q;
  for (; k + 4 < e; k += 8) {
    int c0, c1;
    float w0, w1;
    dec_rec(cw[k], c0, w0);
    dec_rec(cw[k + 4], c1, w1);
    const half4v x0 = *reinterpret_cast<const half4v*>(X + (size_t)c0 * 64 + l * 4);
    const half4v x1 = *reinterpret_cast<const half4v*>(X + (size_t)c1 * 64 + l * 4);
    a = fma4h(w0, x0, a);
    a = fma4h(w1, x1, a);
  }
  if (k < e) {
    int c0;
    float w0;
    dec_rec(cw[k], c0, w0);
    a = fma4h(w0, *reinterpret_cast<const half4v*>(X + (size_t)c0 * 64 + l * 4), a);
  }
#pragma unroll
  for (int j = 0; j < 4; ++j) {
    a[j] += __shfl_xor(a[j], 16, 64);
    a[j] += __shfl_xor(a[j], 32, 64);
  }
  const size_t o = (size_t)r * 64 + l * 4;
  // all quarters load identical 16B slices (broadcast); reduce within each quarter
  const float4v p = *reinterpret_cast<const float4v*>(P + o);
  const float4v qv = *reinterpret_cast<const float4v*>(Q + o);
  float ps = p[0] * p[0] + p[1] * p[1] + p[2] * p[2] + p[3] * p[3];
  float qs = qv[0] * qv[0] + qv[1] * qv[1] + qv[2] * qv[2] + qv[3] * qv[3];
#pragma unroll
  for (int off = 8; off; off >>= 1) {
    ps += __shfl_xor(ps, off, 64);
    qs += __shfl_xor(qs, off, 64);
  }
  const float pn = 0.55f / fmaxf(sqrtf(ps), 1e-12f);
  const float qn = 0.55f / fmaxf(sqrtf(qs), 1e-12f);
  if (q == 0) {
    if (GO) *reinterpret_cast<half4v*>(GO + o) = to_h4(a);
    float4v av = *reinterpret_cast<const float4v*>(accio + o);
#pragma unroll
    for (int j = 0; j < 4; ++j) {
      av[j] = (av[j] + a[j]) * (1.0f / 3.0f) + pn * p[j] + qn * qv[j];
    }
    *reinterpret_cast<float4v*>(accio + o) = av;
  }
}

extern "C" void kernel_launch(void* const* d_in, const int* in_sizes, int n_in,
                              void* d_out, int out_size, void* d_ws, size_t ws_size,
                              hipStream_t stream) {
  const float* image_feats = (const float*)d_in[0];
  const float* text_feats = (const float*)d_in[1];
  const float* user_emb = (const float*)d_in[2];
  const float* item_emb = (const float*)d_in[3];
  const float* W_img = (const float*)d_in[4];
  const float* b_img = (const float*)d_in[5];
  const float* W_txt = (const float*)d_in[6];
  const float* b_txt = (const float*)d_in[7];
  const float* val_ui = (const float*)d_in[8];
  const float* val_iu = (const float*)d_in[9];
  const int* edge_u = (const int*)d_in[10];
  const int* edge_i = (const int*)d_in[11];

  float* out = (float*)d_out;
  float* u_acc = out + OFF_UOUT;
  float* i_acc = out + OFF_IOUT;
  float* img_item = out + OFF_IIT;
  float* txt_item = out + OFF_TIT;
  float* img_user = out + OFF_IUS;
  float* txt_user = out + OFF_TUS;

  // workspace carve-up (~95 MB)
  char* wsb = (char*)d_ws;
  size_t off = 0;
  auto take = [&](size_t bytes) -> void* {
    void* p = wsb + off;
    off += (bytes + 255) & ~(size_t)255;
    return p;
  };
  // fp16 packed gather tables
  _Float16* g_items = (_Float16*)take((size_t)N_ITEMS * 192 * 2);  // {img feat, txt feat, i0}
  _Float16* g_users = (_Float16*)take((size_t)N_USERS * 192 * 2);  // {img_user, txt_user, u1}
  _Float16* g_i1 = (_Float16*)take((size_t)N_ITEMS * 64 * 2);
  _Float16* g_u2 = (_Float16*)take((size_t)N_USERS * 64 * 2);
  unsigned int* cw_u = (unsigned int*)take((size_t)N_EDGES * 4);  // packed {col,fp16 w}
  unsigned int* cw_i = (unsigned int*)take((size_t)N_EDGES * 4);
  int* rs_u = (int*)take((N_USERS + 1) * 4);
  int* rs_i = (int*)take((N_ITEMS + 1) * 4);
  int* cnt_u = (int*)take((size_t)N_USERS * 4);
  int* cnt_i = (int*)take((size_t)N_ITEMS * 4);
  unsigned short* WBimg = (unsigned short*)take((size_t)8192 * 8 * 2);  // 128 KB
  unsigned short* WBtxt = (unsigned short*)take((size_t)3072 * 8 * 2);  // 48 KB
  float* stats = (float*)take(65 * 4);

  // CSR-build scratch, dead after fill — aliased onto later-written fp16 tables:
  // priv (64 slices, 38.4 MB) on g_users (38.4 MB); pe (16 MB) on g_i1+g_u2 (19.2 MB
  // contiguous: both 256-aligned carves with no padding gap).
  int* priv_u = (int*)g_users;                                  // 64 * 100000 * 4 = 25.6 MB
  int* priv_i = (int*)((char*)g_users + (size_t)NPRIV * N_USERS * 4);  // 12.8 MB
  int* pe_u = (int*)g_i1;                                       // 8 MB
  int* pe_i = pe_u + N_EDGES;                                   // 8 MB

  hipMemsetAsync(priv_u, 0, (size_t)NPRIV * (N_USERS + N_ITEMS) * 4, stream);
  hipMemsetAsync(stats, 0, 65 * 4, stream);

  hist_priv_kernel<<<NPRIV, 256, 0, stream>>>(edge_u, edge_i, priv_u, priv_i, pe_u, pe_i);
  const int kblk = (N_USERS + N_ITEMS + 255) / 256;
  sum_priv_kernel<<<kblk, 256, 0, stream>>>(priv_u, priv_i, cnt_u, cnt_i);
  scan2_kernel<<<2, 1024, 0, stream>>>(cnt_u, rs_u, cnt_i, rs_i);
  base_priv_kernel<<<kblk, 256, 0, stream>>>(priv_u, priv_i, rs_u, rs_i);
  const int eblk = (N_EDGES + 255) / 256;
  fill_kernel<<<eblk, 256, 0, stream>>>(edge_u, edge_i, val_ui, val_iu, pe_u, pe_i,
                                        priv_u, priv_i, cw_u, cw_i);

  wswizzle_kernel<<<44, 256, 0, stream>>>(W_img, W_txt, WBimg, WBtxt);
  const int ntiles = 2 * (N_ITEMS / 16);  // 6250
  mfma_gemm_kernel<<<(ntiles + 3) / 4, 256, 0, stream>>>(image_feats, WBimg, b_img,
                                                         text_feats, WBtxt, b_txt, g_items);

  stats_kernel<<<2048, 256, 0, stream>>>(user_emb, item_emb, stats);
  finalize_kernel<<<1, 64, 0, stream>>>(stats);
  normalize_kernel<<<2048, 256, 0, stream>>>(user_emb, item_emb, stats, u_acc, i_acc, g_items);

  // user side: {img_user, txt_user, u1}; u_acc += u1; g_users packed fp16
  spmm_triple_kernel<<<N_USERS / 4, 256, 0, stream>>>(
      rs_u, cw_u, g_items, img_user, txt_user, u_acc, g_users, nullptr, N_USERS);
  // item side: {img_item, txt_item, i1}; i_acc += i1; g_i1 fp16
  spmm_triple_kernel<<<N_ITEMS / 4, 256, 0, stream>>>(
      rs_i, cw_i, g_users, img_item, txt_item, i_acc, nullptr, g_i1, N_ITEMS);
  // u2 = A_ui @ i1 (fp16 out) + fused user epilogue
  spmm_final_kernel<<<N_USERS / 4, 256, 0, stream>>>(
      rs_u, cw_u, g_i1, g_u2, img_user, txt_user, u_acc, N_USERS);
  // i2 = A_iu @ u2 + fused item epilogue
  spmm_final_kernel<<<N_ITEMS / 4, 256, 0, stream>>>(
      rs_i, cw_i, g_u2, nullptr, img_item, txt_item, i_acc, N_ITEMS);
}